// Round 10
// baseline (238.004 us; speedup 1.0000x reference)
//
#include <hip/hip_runtime.h>
#include <hip/hip_bf16.h>

// y[b, c] = (sum_k x[b,k] * W[c % 512, k]) + bias[c]
// R15: R11/R13 base (best, 150.4us: 128x128 tile, split-K=4 -> 512 blocks =
// 2/CU, bf16 DMA staging, 2-stage 64KB ring, counted vmcnt(8)) with the
// combine FUSED into the gemm via the R6-proven NO-SPIN ticket protocol:
//   - all 4 splits of a (mt,nt) tile are on ONE XCD (R11 block map), so
//     partner partials are home-L2 dirty lines (R6's failure was cross-XCD).
//   - every split stores its fp32 partial into replica slot #sp of out
//     (storage the tile owns anyway), __syncthreads (drains stores),
//     __threadfence, acq_rel agent-scope ticket. Last arrival (old==3) is
//     the winner: reads the 3 partner slots (192 KB, L2-local), adds its own
//     acc (still in registers), adds bias, writes all 8 replica slots.
//   - no spin -> no deadlock risk; losers exit. Read-before-write per
//     element by the same thread -> in-place safe.
//   - eliminates combine_kernel: its launch gap + 32 MB partial re-read +
//     bias re-read. K-loop/staging/swizzle: R11 verbatim.
// Geometry is closed: staged bytes ~ (1/BM+1/BN), minimized at 128x128 under
// the BM+BN<=256 LDS constraint; BK=32 degrades DMA rate (R12+R14 confirm).
// Fusion of x-convert closed (R7/R9/R12 all >= +30us). fp8 closed (absmax).
// Pre-committed exit: if total >= 150 or fail, R13 is the roofline.

typedef __bf16 bf8 __attribute__((ext_vector_type(8)));
typedef float f4 __attribute__((ext_vector_type(4)));
typedef unsigned int uint;
typedef unsigned short ushort;

constexpr int M = 4096;
constexpr int K = 4096;
constexpr int NS = 512;
constexpr int OUTF = 4096;
constexpr int BM = 128, BN = 128, BK = 64;
constexpr int SPLITS = 4;
constexpr int KSPL = K / SPLITS;    // 1024
constexpr int NITER = KSPL / BK;    // 16
constexpr int MT = M / BM;          // 32
constexpr int NT = NS / BN;         // 4
constexpr int NTILES = MT * NT;     // 128

#define PERM_HI2(hi, lo) __builtin_amdgcn_perm((hi), (lo), 0x07060302u)
// s_waitcnt imm: vmcnt[3:0]|expcnt[6:4]|lgkmcnt[11:8]|vmcnt[15:14]
#define WAITCNT_VM8 0xF78   // vmcnt<=8: tile kk's 8 DMAs drained, kk+1 in flight
#define WAITCNT_VM0 0xF70

__device__ __forceinline__ void async16(const ushort* g, ushort* l) {
  __builtin_amdgcn_global_load_lds(
      (const __attribute__((address_space(1))) void*)g,
      (__attribute__((address_space(3))) void*)l, 16, 0, 0);
}

// fp32 -> bf16 (truncate), 8 elems/thread; covers x then W exactly.
// Block 0 additionally zeroes the 128 split-K tickets (per graph replay).
__global__ __launch_bounds__(256)
void convert_kernel(const float* __restrict__ x, const float* __restrict__ w,
                    ushort* __restrict__ xb, ushort* __restrict__ wb,
                    uint* __restrict__ tickets) {
  if (blockIdx.x == 0 && threadIdx.x < NTILES) tickets[threadIdx.x] = 0u;
  const size_t i = (size_t)blockIdx.x * 256 + threadIdx.x;
  constexpr size_t NX = (size_t)M * K / 8;
  const float* src;
  ushort* dst;
  if (i < NX) { src = x + i * 8; dst = xb + i * 8; }
  else        { const size_t j = i - NX; src = w + j * 8; dst = wb + j * 8; }
  const uint4 a = *reinterpret_cast<const uint4*>(src);
  const uint4 b = *reinterpret_cast<const uint4*>(src + 4);
  uint4 o;
  o.x = PERM_HI2(a.y, a.x); o.y = PERM_HI2(a.w, a.z);
  o.z = PERM_HI2(b.y, b.x); o.w = PERM_HI2(b.w, b.z);
  *reinterpret_cast<uint4*>(dst) = o;
}

__global__ __launch_bounds__(256, 2)
void gemm_kernel(const ushort* __restrict__ xb, const ushort* __restrict__ wb,
                 const float* __restrict__ bias, float* __restrict__ out,
                 uint* __restrict__ tickets) {
  __shared__ __align__(16) ushort As[2][BM * BK];   // 16 KB/stage
  __shared__ __align__(16) ushort Bs[2][BN * BK];   // 16 KB/stage  -> 64 KB

  // block map (R11): b = (mt&7) + 8*((mt>>3)*16 + sp*4 + nt)
  // -> the 16 blocks of one mt share b&7 (one XCD): x-slab fetched once/XCD,
  //    and the 4 splits of each (mt,nt) exchange partials in home L2.
  const int b   = blockIdx.x;          // 512 blocks
  const int low = b & 7, h = b >> 3;   // h in [0,64)
  const int mt  = (h >> 4) * 8 + low;  // 0..31
  const int sp  = (h >> 2) & 3;        // split 0..3
  const int nt  = h & 3;               // 0..3

  const int tid  = threadIdx.x;
  const int wv   = tid >> 6;           // 0..3
  const int lane = tid & 63;
  const int lr   = lane & 15;
  const int lq   = lane >> 4;

  // DMA staging (R11): per matrix, tile = 128 rows x 64 bf16 = 1024 16B-chunks
  // (8/row); LDS chunk c holds global chunk ((c&7)^(r&7)) of row r=c>>3.
  int goff[4], lloc[4];
#pragma unroll
  for (int j = 0; j < 4; ++j) {
    const int c = (wv * 4 + j) * 64 + lane;
    const int r = c >> 3;
    const int g = (c & 7) ^ (r & 7);
    goff[j] = r * K + g * 8;
    lloc[j] = c * 8;
  }

  const ushort* xT = xb + (size_t)(mt * BM) * K + sp * KSPL;
  const ushort* wT = wb + (size_t)(nt * BN) * K + sp * KSPL;

  auto issue = [&](int tile, int stg) {
    const int ko = tile * BK;
#pragma unroll
    for (int j = 0; j < 4; ++j) {
      async16(xT + ko + goff[j], &As[stg][lloc[j]]);
      async16(wT + ko + goff[j], &Bs[stg][lloc[j]]);
    }
  };

  const int wm = (wv & 1) * 64;        // 2x2 wave grid, wave tile 64x64
  const int wn = (wv >> 1) * 64;

  f4 acc[4][4] = {};

  // prologue: tiles 0,1 into stages 0,1 (8 DMAs/wave each)
  issue(0, 0);
  issue(1, 1);

  int st = 0;
  for (int kk = 0; kk < NITER; ++kk) {
    if (kk + 1 < NITER) __builtin_amdgcn_s_waitcnt(WAITCNT_VM8);
    else                __builtin_amdgcn_s_waitcnt(WAITCNT_VM0);
    __builtin_amdgcn_s_barrier();      // publish tile kk (stage st)
    asm volatile("" ::: "memory");

    const ushort* aT = As[st];
    const ushort* bT = Bs[st];
#pragma unroll
    for (int t = 0; t < 2; ++t) {
      const int sc = ((t * 4 + lq) ^ (lr & 7)) * 8;   // R5-proven read swizzle
      bf8 af[4], bfv[4];
#pragma unroll
      for (int mf = 0; mf < 4; ++mf)
        af[mf] = *reinterpret_cast<const bf8*>(&aT[(wm + mf * 16 + lr) * BK + sc]);
#pragma unroll
      for (int nf = 0; nf < 4; ++nf)
        bfv[nf] = *reinterpret_cast<const bf8*>(&bT[(wn + nf * 16 + lr) * BK + sc]);
#pragma unroll
      for (int mf = 0; mf < 4; ++mf)
#pragma unroll
        for (int nf = 0; nf < 4; ++nf)
          acc[mf][nf] = __builtin_amdgcn_mfma_f32_16x16x32_bf16(af[mf], bfv[nf], acc[mf][nf], 0, 0, 0);
    }
    asm volatile("" ::: "memory");
    __builtin_amdgcn_s_barrier();      // all waves done READING stage st
    asm volatile("" ::: "memory");
    if (kk + 2 < NITER) issue(kk + 2, st);   // stage st now reusable
    st ^= 1;
  }

  // ---- 1) store fp32 partial into replica slot #sp of out (R11) ----
  // C/D layout (16x16x32, verified): row = wm+mf*16+lq*4+r, col = wn+nf*16+lr.
  const int colb = nt * BN + wn;       // column base within the 512-block
  float* pb = out + (size_t)(mt * BM) * OUTF + sp * NS + colb;
#pragma unroll
  for (int mf = 0; mf < 4; ++mf)
#pragma unroll
    for (int nf = 0; nf < 4; ++nf)
#pragma unroll
      for (int r = 0; r < 4; ++r)
        pb[(size_t)(wm + mf * 16 + lq * 4 + r) * OUTF + nf * 16 + lr] =
            acc[mf][nf][r];

  // ---- 2) ticket (R6-proven, no spin): last arrival combines ----
  __syncthreads();                     // block stores drained (vmcnt before barrier)
  uint* s_oldp = reinterpret_cast<uint*>(&As[0][0]);   // K-loop LDS is dead
  if (tid == 0) {
    __threadfence();                   // release partials device-wide
    *s_oldp = __hip_atomic_fetch_add(&tickets[mt * NT + nt], 1u,
                                     __ATOMIC_ACQ_REL, __HIP_MEMORY_SCOPE_AGENT);
  }
  __syncthreads();
  if (*s_oldp != SPLITS - 1) return;   // losers exit
  if (tid == 0) __threadfence();       // acquire partners' partials
  __syncthreads();

  // ---- 3) winner: own acc + 3 partner slots (L2-local) + bias -> 8 reps ----
  // Per element: read partner addrs, then write the 8 replica addrs (which
  // include those partner addrs) -- same-thread read-before-write, disjoint
  // across threads. Coalesced in 16-lane 64 B runs.
  float bv[8][4];                      // bias[rep][nf] for this thread's cols
#pragma unroll
  for (int rep = 0; rep < 8; ++rep)
#pragma unroll
    for (int nf = 0; nf < 4; ++nf)
      bv[rep][nf] = bias[rep * NS + colb + nf * 16 + lr];

  float* ob = out + (size_t)(mt * BM) * OUTF + colb;
#pragma unroll
  for (int mf = 0; mf < 4; ++mf)
#pragma unroll
    for (int r = 0; r < 4; ++r) {
      const size_t rowoff = (size_t)(wm + mf * 16 + lq * 4 + r) * OUTF;
#pragma unroll
      for (int nf = 0; nf < 4; ++nf) {
        const int co = nf * 16 + lr;
        float s = acc[mf][nf][r];
#pragma unroll
        for (int p = 0; p < SPLITS; ++p)
          if (p != sp) s += ob[rowoff + p * NS + co];
#pragma unroll
        for (int rep = 0; rep < 8; ++rep)
          ob[rowoff + rep * NS + co] = s + bv[rep][nf];
      }
    }
}

extern "C" void kernel_launch(void* const* d_in, const int* in_sizes, int n_in,
                              void* d_out, int out_size, void* d_ws, size_t ws_size,
                              hipStream_t stream) {
  (void)in_sizes; (void)n_in; (void)out_size; (void)ws_size;
  const float* x    = (const float*)d_in[0];
  const float* w    = (const float*)d_in[1];
  const float* bias = (const float*)d_in[2];
  float* out = (float*)d_out;

  ushort* xb = (ushort*)d_ws;                       // 32 MB bf16 x
  ushort* wb = (ushort*)d_ws + (size_t)M * K;       // 4 MB bf16 W
  uint* tickets = (uint*)(wb + (size_t)NS * K);     // 512 B (ws >= 36 MB + 512 B)

  constexpr int conv_blocks = (int)(((size_t)M * K / 8 + (size_t)NS * K / 8) / 256); // 9216
  convert_kernel<<<dim3(conv_blocks), dim3(256), 0, stream>>>(x, w, xb, wb, tickets);
  gemm_kernel<<<dim3(MT * NT * SPLITS), dim3(256), 0, stream>>>(xb, wb, bias, out, tickets);
}